// Round 1
// baseline (2236.374 us; speedup 1.0000x reference)
//
#include <hip/hip_runtime.h>

#define HH 512
#define WW 512
#define SS (HH * WW)          // 262144 elements per plane
#define P16N (16 * SS)        // 16 planes (one input's batch)

// ---------------- kernels ----------------

__device__ __forceinline__ float grayAt(const float* __restrict__ rgb, int imgBase, int pix) {
    return 0.299f * rgb[imgBase + pix]
         + 0.587f * rgb[imgBase + SS + pix]
         + 0.114f * rgb[imgBase + 2 * SS + pix];
}

// Fused gray + forward difference. dir 0 = x (cols), 1 = y (rows).
// g[...,last] = gray (neighbor padded with 0), matching jnp.pad semantics.
__global__ void grad_kernel(const float* __restrict__ rgb, float* __restrict__ dst, int dir) {
    int idx = blockIdx.x * 256 + threadIdx.x;           // [0, 16*SS)
    int img = idx >> 18;                                // SS = 2^18
    int pix = idx & (SS - 1);
    int i = pix >> 9, j = pix & (WW - 1);
    int imgBase = img * 3 * SS;
    float a = grayAt(rgb, imgBase, pix);
    float b = 0.f;
    if (dir == 0) { if (j < WW - 1) b = grayAt(rgb, imgBase, pix + 1); }
    else          { if (i < HH - 1) b = grayAt(rgb, imgBase, pix + WW); }
    dst[idx] = a - b;
}

// OP: 0=max, 1=min, 2=sum. Valid-only window (matches -inf / zero padding semantics).
template <int OP, bool PREABS>
__global__ void row_pool(const float* __restrict__ src, float* __restrict__ dst, int r, int total) {
    int idx = blockIdx.x * 256 + threadIdx.x;
    if (idx >= total) return;
    int j = idx & (WW - 1);
    int rowBase = idx - j;
    int lo = max(j - r, 0), hi = min(j + r, WW - 1);
    float acc = (OP == 0) ? -__builtin_inff() : (OP == 1 ? __builtin_inff() : 0.f);
    for (int jj = lo; jj <= hi; ++jj) {
        float v = src[rowBase + jj];
        if (PREABS) v = fabsf(v);
        if (OP == 0)      acc = fmaxf(acc, v);
        else if (OP == 1) acc = fminf(acc, v);
        else              acc += v;
    }
    dst[idx] = acc;
}

template <int OP>
__global__ void col_pool(const float* __restrict__ src, float* __restrict__ dst, int r, int total) {
    int idx = blockIdx.x * 256 + threadIdx.x;
    if (idx >= total) return;
    int pix = idx & (SS - 1);
    int i = pix >> 9;
    int base = idx - (i << 9);                          // plane base + j
    int lo = max(i - r, 0), hi = min(i + r, HH - 1);
    float acc = (OP == 0) ? -__builtin_inff() : __builtin_inff();
    for (int ii = lo; ii <= hi; ++ii) {
        float v = src[base + ii * WW];
        if (OP == 0) acc = fmaxf(acc, v);
        else         acc = fminf(acc, v);
    }
    dst[idx] = acc;
}

// Column pass of avgpool: sums rows of the row-sum image, divides by valid count.
template <bool POSTABS>
__global__ void col_avg(const float* __restrict__ src, float* __restrict__ dst, int r, int total) {
    int idx = blockIdx.x * 256 + threadIdx.x;
    if (idx >= total) return;
    int pix = idx & (SS - 1);
    int i = pix >> 9, j = pix & (WW - 1);
    int base = idx - (i << 9);
    int lo = max(i - r, 0), hi = min(i + r, HH - 1);
    float acc = 0.f;
    for (int ii = lo; ii <= hi; ++ii) acc += src[base + ii * WW];
    int ch = hi - lo + 1;
    int cw = min(j + r, WW - 1) - max(j - r, 0) + 1;
    float v = acc / (float)(ch * cw);
    if (POSTABS) v = fabsf(v);
    dst[idx] = v;
}

// gn1 = (|g| - gmin1) / (|gmax1 - gmin1| + eps); dst may alias gmin1.
__global__ void gn1_kernel(const float* __restrict__ g, const float* __restrict__ gmax1,
                           const float* __restrict__ gmin1, float* __restrict__ dst, int total) {
    int idx = blockIdx.x * 256 + threadIdx.x;
    if (idx >= total) return;
    float ga = fabsf(g[idx]);
    float mn = gmin1[idx];
    dst[idx] = (ga - mn) / (fabsf(gmax1[idx] - mn) + 1e-4f);
}

// map = ((go - pmin)/(|pmax - pmin| + eps) + 0.01) * gn1; dst may alias pmax.
__global__ void final_map(const float* __restrict__ go, const float* __restrict__ pmin,
                          const float* __restrict__ pmax, const float* __restrict__ gn1,
                          float* __restrict__ dst, int total) {
    int idx = blockIdx.x * 256 + threadIdx.x;
    if (idx >= total) return;
    float pn = pmin[idx];
    float gn = (go[idx] - pn) / (fabsf(pmax[idx] - pn) + 1e-4f);
    dst[idx] = (gn + 0.01f) * gn1[idx];
}

// sum(mR * exp(-10 mR) * exp(-10 mL)) * scale, atomically accumulated into out[0].
__global__ void reduce_pair(const float* __restrict__ mR, const float* __restrict__ mL,
                            float* __restrict__ out, int total, float scale) {
    int idx = blockIdx.x * 256 + threadIdx.x;
    float v = 0.f;
    if (idx < total) {
        float a = mR[idx], b = mL[idx];
        v = a * expf(-10.f * a) * expf(-10.f * b);
    }
    for (int off = 32; off; off >>= 1) v += __shfl_down(v, off);   // wave64 reduce
    __shared__ float lds[4];
    int lane = threadIdx.x & 63, wv = threadIdx.x >> 6;
    if (lane == 0) lds[wv] = v;
    __syncthreads();
    if (threadIdx.x == 0) {
        float s = lds[0] + lds[1] + lds[2] + lds[3];
        atomicAdd(out, s * scale);
    }
}

// ---------------- host orchestration ----------------

static inline int nblk(int total) { return (total + 255) / 256; }

// Separable-pool pipeline on `total` stacked plane elements, B0 holds g on entry.
// Final per-pixel map is written to mapDst.
static void run_pipeline(float* B0, float* B1, float* B2, float* B3, float* B4,
                         float* mapDst, int total, hipStream_t stream) {
    int g = nblk(total);
    // pmax1 = maxpool9(|g|) -> B3 ; pmin1 = minpool9(|g|) -> B4
    row_pool<0, true ><<<g, 256, 0, stream>>>(B0, B2, 4, total);
    col_pool<0       ><<<g, 256, 0, stream>>>(B2, B3, 4, total);
    row_pool<1, true ><<<g, 256, 0, stream>>>(B0, B2, 4, total);
    col_pool<1       ><<<g, 256, 0, stream>>>(B2, B4, 4, total);
    // gmax1 = avg17(pmax1) -> B3 ; gmin1 = avg17(pmin1) -> B4
    row_pool<2, false><<<g, 256, 0, stream>>>(B3, B2, 8, total);
    col_avg<false    ><<<g, 256, 0, stream>>>(B2, B3, 8, total);
    row_pool<2, false><<<g, 256, 0, stream>>>(B4, B2, 8, total);
    col_avg<false    ><<<g, 256, 0, stream>>>(B2, B4, 8, total);
    // gn1 -> B4   (reads g=B0, gmax1=B3, gmin1=B4)
    gn1_kernel<<<g, 256, 0, stream>>>(B0, B3, B4, B4, total);
    // go = |avg5(g)| -> B3   (B0 free afterwards)
    row_pool<2, false><<<g, 256, 0, stream>>>(B0, B2, 2, total);
    col_avg<true     ><<<g, 256, 0, stream>>>(B2, B3, 2, total);
    // pmax = avg7(max7(go)) -> B0
    row_pool<0, false><<<g, 256, 0, stream>>>(B3, B2, 3, total);
    col_pool<0       ><<<g, 256, 0, stream>>>(B2, B0, 3, total);
    row_pool<2, false><<<g, 256, 0, stream>>>(B0, B2, 3, total);
    col_avg<false    ><<<g, 256, 0, stream>>>(B2, B0, 3, total);
    // pmin = avg7(min7(go)) -> B1
    row_pool<1, false><<<g, 256, 0, stream>>>(B3, B2, 3, total);
    col_pool<1       ><<<g, 256, 0, stream>>>(B2, B1, 3, total);
    row_pool<2, false><<<g, 256, 0, stream>>>(B1, B2, 3, total);
    col_avg<false    ><<<g, 256, 0, stream>>>(B2, B1, 3, total);
    // map = ((go - pmin)/(|pmax - pmin| + eps) + 0.01) * gn1 -> mapDst
    final_map<<<g, 256, 0, stream>>>(B3, B1, B0, B4, mapDst, total);
}

extern "C" void kernel_launch(void* const* d_in, const int* in_sizes, int n_in,
                              void* d_out, int out_size, void* d_ws, size_t ws_size,
                              hipStream_t stream) {
    const float* Rrgb = (const float*)d_in[0];
    const float* Lrgb = (const float*)d_in[1];
    float* out = (float*)d_out;
    float* w = (float*)d_ws;
    const float scale = 1.f / (float)P16N;   // mean over (16,1,512,512)

    hipMemsetAsync(out, 0, sizeof(float) * (size_t)out_size, stream);

    size_t need32 = (size_t)5 * 32 * SS * sizeof(float);   // ~168 MB
    if (ws_size >= need32) {
        // 32 stacked planes per direction: [0..16) = R, [16..32) = low
        int total = 32 * SS;
        float* B0 = w;
        float* B1 = B0 + (size_t)32 * SS;
        float* B2 = B1 + (size_t)32 * SS;
        float* B3 = B2 + (size_t)32 * SS;
        float* B4 = B3 + (size_t)32 * SS;
        for (int dir = 0; dir < 2; ++dir) {
            grad_kernel<<<nblk(P16N), 256, 0, stream>>>(Rrgb, B0, dir);
            grad_kernel<<<nblk(P16N), 256, 0, stream>>>(Lrgb, B0 + P16N, dir);
            run_pipeline(B0, B1, B2, B3, B4, B0, total, stream);
            reduce_pair<<<nblk(P16N), 256, 0, stream>>>(B0, B0 + P16N, out, P16N, scale);
        }
    } else {
        // fallback: 16 planes per chunk, extra hold buffer (~101 MB total)
        int total = P16N;
        float* B0 = w;
        float* B1 = B0 + (size_t)P16N;
        float* B2 = B1 + (size_t)P16N;
        float* B3 = B2 + (size_t)P16N;
        float* B4 = B3 + (size_t)P16N;
        float* HOLD = B4 + (size_t)P16N;
        for (int dir = 0; dir < 2; ++dir) {
            grad_kernel<<<nblk(P16N), 256, 0, stream>>>(Rrgb, B0, dir);
            run_pipeline(B0, B1, B2, B3, B4, HOLD, total, stream);
            grad_kernel<<<nblk(P16N), 256, 0, stream>>>(Lrgb, B0, dir);
            run_pipeline(B0, B1, B2, B3, B4, B0, total, stream);
            reduce_pair<<<nblk(P16N), 256, 0, stream>>>(HOLD, B0, out, P16N, scale);
        }
    }
}